// Round 5
// baseline (4541.946 us; speedup 1.0000x reference)
//
#include <hip/hip_runtime.h>
#include <hip/hip_cooperative_groups.h>
#include <math.h>
#include <stdint.h>

namespace cg = cooperative_groups;

// Problem constants
#define B_   256
#define T_   128
#define NIN_ 1024
#define H1_  512
#define E_   256
#define A_   16
#define MT_  (B_ * T_)   // 32768 rows, t-major: m = t*B_ + b

typedef unsigned short ushort_t;
typedef __attribute__((ext_vector_type(8))) short   short8;
typedef __attribute__((ext_vector_type(8))) __bf16  bf16x8;
typedef __attribute__((ext_vector_type(4))) float   f32x4;

union frag8 { short8 s; bf16x8 b; };

__device__ __forceinline__ ushort_t f2bf(float f) {
  union { float f; unsigned u; } v; v.f = f;
  unsigned r = (v.u + 0x7FFFu + ((v.u >> 16) & 1u)) >> 16;   // RNE
  return (ushort_t)r;
}

// ---------------- workspace layout (bytes) ----------------
// C0 fp32 [T][5][256 col][256 row] = 160MB at 0. Chunks: 0=henc 1=rpre0 2=zpre0 3=hn0 4=inn.
// Written late (penc_cm + 4 col-major GEMMs); earlier phases overlay its space.
static constexpr size_t OFF_C0    = 0;
static constexpr size_t OFF_OBSB  = 0;            // bf16 [32768][1024] 64MB, dead after G1
static constexpr size_t OFF_Y     = 67108864;     // fp32 [32768][512] 64MB, dead after bn2
static constexpr size_t OFF_YG    = 67108864;     // fp32 [32768][256] 32MB (overlays Y)
static constexpr size_t OFF_XB    = 134217728;    // bf16 [32768][512] 32MB, dead after G3
static constexpr size_t OFF_XG    = 167772160;    // bf16 [32768][256] 16MB (outside C0)
static constexpr size_t OFF_PENCB = 184549376;    // bf16 [32768][256] 16MB (outside C0)
static constexpr size_t OFF_AE    = 201326592;    // fp32 [32768][16] 2MB -> ends 203423744
static constexpr size_t OFF_W1T   = 203423744;    // bf16 [512][1024]  1048576 -> 204472320
static constexpr size_t OFF_W2T   = 204472320;    // bf16 [512][512]    524288 -> 204996608
static constexpr size_t OFF_W3T   = 204996608;    // bf16 [256][512]    262144 -> 205258752
static constexpr size_t OFF_WIHT  = 205258752;    // bf16 [768][256]    393216 -> 205651968
static constexpr size_t OFF_WHHT  = 205651968;    // bf16 [768][256]    393216 -> 206045184
static constexpr size_t OFF_WCT   = 206045184;    // bf16 [1024][256]   524288 -> 206569472
static constexpr size_t OFF_BSUM  = 206569472;    // fp32 [768]           3072 -> 206572544
static constexpr size_t OFF_H0    = 206572544;    // bf16 [2][256][256] 131072 -> 206703616

// ---------------- prologue kernels ----------------

__global__ __launch_bounds__(256) void cast_obs_k(const float* __restrict__ obs,
                                                  ushort_t* __restrict__ out) {
  int row_in = blockIdx.x;              // b*T + t
  int b = row_in / T_, t = row_in - b * T_;
  const float4* s4 = (const float4*)(obs + (size_t)row_in * NIN_);
  float4 v = s4[threadIdx.x];
  ushort_t* d = out + (size_t)(t * B_ + b) * NIN_ + threadIdx.x * 4;
  d[0] = f2bf(v.x); d[1] = f2bf(v.y); d[2] = f2bf(v.z); d[3] = f2bf(v.w);
}

__global__ __launch_bounds__(256) void transpose_cast_k(const float* __restrict__ in,
                                                        ushort_t* __restrict__ out,
                                                        int R, int C) {
  __shared__ float tile[32][33];
  int c0 = blockIdx.x * 32, r0 = blockIdx.y * 32;
  int tx = threadIdx.x & 31, ty = threadIdx.x >> 5;
  for (int i = 0; i < 4; i++) {
    int r = r0 + ty * 4 + i;
    if (r < R && (c0 + tx) < C) tile[ty * 4 + i][tx] = in[(size_t)r * C + c0 + tx];
  }
  __syncthreads();
  for (int i = 0; i < 4; i++) {
    int c = c0 + ty * 4 + i, r = r0 + tx;
    if (c < C && r < R) out[(size_t)c * R + r] = f2bf(tile[tx][ty * 4 + i]);
  }
}

__global__ __launch_bounds__(256) void wct_a_k(const float* __restrict__ Whe,
                                               ushort_t* __restrict__ Wct) {
  int c = blockIdx.x, k = threadIdx.x;
  Wct[(size_t)c * 256 + k] = f2bf(Whe[(size_t)k * 256 + c]);
}

__global__ __launch_bounds__(256) void wct_b_k(const float* __restrict__ Whe,
                                               const float* __restrict__ Whh,
                                               ushort_t* __restrict__ Wct) {
  int c = blockIdx.x;   // 0..767 (gh column)
  int k = threadIdx.x;  // h feature
  float acc = 0.f;
  for (int j = 0; j < 256; j++)
    acc += Whe[(size_t)k * 256 + j] * Whh[(size_t)j * 768 + c];
  Wct[(size_t)(256 + c) * 256 + k] = f2bf(acc);
}

__global__ void bsum_k(const float* __restrict__ bih, const float* __restrict__ bhh,
                       float* __restrict__ bs) {
  int i = blockIdx.x * 256 + threadIdx.x;
  if (i < 768) bs[i] = bih[i] + bhh[i];
}

__global__ void zero_k(ushort_t* p, int n) {
  int i = blockIdx.x * 256 + threadIdx.x;
  if (i < n) p[i] = 0;
}

__global__ __launch_bounds__(256) void ae_k(const float* __restrict__ actions,
                                            const float* __restrict__ Wae,
                                            const float* __restrict__ bae,
                                            float* __restrict__ AE) {
  int idx = blockIdx.x * 256 + threadIdx.x;
  int m = idx >> 4, k2 = idx & 15;
  int t = m >> 8, b = m & 255;
  const float* arow = actions + ((size_t)b * T_ + t) * A_;
  float acc = bae[k2];
  for (int k = 0; k < 16; k++) acc += arow[k] * Wae[k * 16 + k2];
  AE[(size_t)m * 16 + k2] = acc;
}

// Pencb[m][j] (bf16, row-major, GEMM A-operand) = bhe[j] + (t>0 ? AE[t-1,b,:]@Whe_a[:,j] : 0)
__global__ __launch_bounds__(256) void penc_rm_k(const float* __restrict__ AE,
                                                 const float* __restrict__ Whe,
                                                 const float* __restrict__ bhe,
                                                 ushort_t* __restrict__ Pencb) {
  int m = blockIdx.x;          // t*B + b
  int j = threadIdx.x;         // 0..255
  __shared__ float a[16];
  if (threadIdx.x < 16)
    a[threadIdx.x] = (m >= B_) ? AE[(size_t)(m - B_) * 16 + threadIdx.x] : 0.f;
  __syncthreads();
  float acc = bhe[j];
  if (m >= B_) {
    for (int k = 0; k < 16; k++) acc += a[k] * Whe[(size_t)(256 + k) * 256 + j];
  }
  Pencb[(size_t)m * 256 + j] = f2bf(acc);
}

// C0 chunk0 (henc, fp32, col-major per t): one block per t, thread = row b, loop cols j.
__global__ __launch_bounds__(256) void penc_cm_k(const float* __restrict__ AE,
                                                 const float* __restrict__ Whe,
                                                 const float* __restrict__ bhe,
                                                 float* __restrict__ C0) {
  int t = blockIdx.x, b = threadIdx.x;
  __shared__ float AEs[256][17];
  __shared__ float WheS[16][256];
  if (t > 0) {
    const float4* src = (const float4*)(AE + (size_t)((t - 1) * 256 + b) * 16);
    for (int v = 0; v < 4; v++) {
      float4 x = src[v];
      AEs[b][v * 4 + 0] = x.x; AEs[b][v * 4 + 1] = x.y;
      AEs[b][v * 4 + 2] = x.z; AEs[b][v * 4 + 3] = x.w;
    }
  } else {
    for (int k = 0; k < 16; k++) AEs[b][k] = 0.f;
  }
  for (int idx = threadIdx.x; idx < 4096; idx += 256) {
    int k = idx >> 8, j = idx & 255;
    WheS[k][j] = Whe[(size_t)(256 + k) * 256 + j];
  }
  __syncthreads();
  float* out = C0 + (size_t)t * 5 * 65536;
  for (int j = 0; j < 256; j++) {
    float acc = bhe[j];
#pragma unroll
    for (int k = 0; k < 16; k++) acc += AEs[b][k] * WheS[k][j];
    out[(size_t)j * 256 + b] = acc;
  }
}

// per-t BatchNorm (training, biased var) + ELU, fp32 in -> bf16 out
__global__ __launch_bounds__(512) void bn_elu_k(const float* __restrict__ Y,
                                                const float* __restrict__ g,
                                                const float* __restrict__ be,
                                                ushort_t* __restrict__ Xb) {
  int t = blockIdx.x, f = threadIdx.x;
  const float* base = Y + (size_t)t * B_ * H1_;
  float s = 0.f, ss = 0.f;
  for (int b = 0; b < B_; b++) {
    float v = base[(size_t)b * H1_ + f];
    s += v; ss += v * v;
  }
  float mu  = s * (1.f / B_);
  float var = ss * (1.f / B_) - mu * mu;
  float inv = 1.f / sqrtf(var + 1e-5f);
  float sc = g[f] * inv, sh = be[f] - mu * sc;
  ushort_t* ob = Xb + (size_t)t * B_ * H1_;
  for (int b = 0; b < B_; b++) {
    float v = base[(size_t)b * H1_ + f] * sc + sh;
    float e = v > 0.f ? v : (expf(v) - 1.f);
    ob[(size_t)b * H1_ + f] = f2bf(e);
  }
}

__global__ __launch_bounds__(256) void cast_k(const float* __restrict__ in,
                                              ushort_t* __restrict__ out, long n) {
  long i = (long)blockIdx.x * 256 + threadIdx.x;
  if (i < n) out[i] = f2bf(in[i]);
}

// ---------------- bf16 MFMA GEMM: C (+)= A . Bt^T + bias ----------------
// cmode 0: row-major C with ldc. cmode 1: col-major-per-t C0 chunks (chunk = cbase + n>>8),
// float4 epilogue stores. 64x64 tile, BK=32, 256 threads.
__global__ __launch_bounds__(256) void gemm_bt_k(const ushort_t* __restrict__ A, int lda,
                                                 const ushort_t* __restrict__ Bt, int ldb,
                                                 float* __restrict__ C, int ldc,
                                                 const float* __restrict__ bias,
                                                 int K, int accum, int cmode, int cchunk) {
  __shared__ __align__(16) ushort_t As[64][40];
  __shared__ __align__(16) ushort_t Bs[64][40];
  int tid = threadIdx.x;
  int wave = tid >> 6, lane = tid & 63;
  int q = lane >> 4, l15 = lane & 15;
  int wr = wave >> 1, wc = wave & 1;
  int m0 = blockIdx.x * 64, n0 = blockIdx.y * 64;
  f32x4 acc[2][2] = {};
  int r = tid >> 2, seg = tid & 3;
  const ushort_t* aSrc = A + (size_t)(m0 + r) * lda + seg * 8;
  const ushort_t* bSrc = Bt + (size_t)(n0 + r) * ldb + seg * 8;
  for (int k0 = 0; k0 < K; k0 += 32) {
    *(short8*)&As[r][seg * 8] = *(const short8*)(aSrc + k0);
    *(short8*)&Bs[r][seg * 8] = *(const short8*)(bSrc + k0);
    __syncthreads();
    frag8 a0, a1, b0, b1;
    a0.s = *(const short8*)&As[wr * 32 + l15][q * 8];
    a1.s = *(const short8*)&As[wr * 32 + 16 + l15][q * 8];
    b0.s = *(const short8*)&Bs[wc * 32 + l15][q * 8];
    b1.s = *(const short8*)&Bs[wc * 32 + 16 + l15][q * 8];
    acc[0][0] = __builtin_amdgcn_mfma_f32_16x16x32_bf16(a0.b, b0.b, acc[0][0], 0, 0, 0);
    acc[0][1] = __builtin_amdgcn_mfma_f32_16x16x32_bf16(a0.b, b1.b, acc[0][1], 0, 0, 0);
    acc[1][0] = __builtin_amdgcn_mfma_f32_16x16x32_bf16(a1.b, b0.b, acc[1][0], 0, 0, 0);
    acc[1][1] = __builtin_amdgcn_mfma_f32_16x16x32_bf16(a1.b, b1.b, acc[1][1], 0, 0, 0);
    __syncthreads();
  }
  for (int at = 0; at < 2; at++)
    for (int bt = 0; bt < 2; bt++) {
      int mb = m0 + wr * 32 + at * 16 + q * 4;       // C/D: row = quad*4+i
      int n  = n0 + wc * 32 + bt * 16 + l15;         //      col = lane&15
      float bv = bias ? bias[n] : 0.f;
      if (cmode == 0) {
        for (int i = 0; i < 4; i++) {
          size_t idx = (size_t)(mb + i) * ldc + n;
          float v = acc[at][bt][i] + bv;
          if (accum) v += C[idx];
          C[idx] = v;
        }
      } else {
        int tt = mb >> 8, b = mb & 255;               // rows q*4..q*4+3 contiguous in b
        size_t idx = (((size_t)tt * 5 + cchunk + (n >> 8)) * 256 + (n & 255)) * 256 + b;
        float4 v;
        v.x = acc[at][bt][0] + bv; v.y = acc[at][bt][1] + bv;
        v.z = acc[at][bt][2] + bv; v.w = acc[at][bt][3] + bv;
        if (accum) {
          float4 p = *(const float4*)&C[idx];
          v.x += p.x; v.y += p.y; v.z += p.z; v.w += p.w;
        }
        *(float4*)&C[idx] = v;
      }
    }
}

// ---------------- persistent GRU recurrence (cooperative, grid.sync) ----------------
// 256 blocks x 64 threads (1 wave). Block (rb = bid&15, cg = bid>>4): rows rb*16..+15,
// cols cg*16..+15 of all 5 chunks. Weights persistent in registers (32 frag8 = 128 VGPRs).
// C0 for step t+1 register-prefetched before the MFMA loop (overlaps compute + sync).
__global__ __launch_bounds__(64, 1) void gru_seq_k(const ushort_t* __restrict__ Wct,
                                                   const float* __restrict__ C0,
                                                   ushort_t* __restrict__ hbuf,
                                                   float* __restrict__ outF) {
  cg::grid_group grid = cg::this_grid();
  int lane = threadIdx.x & 63;
  int q = lane >> 4, l15 = lane & 15;
  int rb = blockIdx.x & 15, cgp = blockIdx.x >> 4;

  // persistent B-fragments: 4 weight chunks x 8 k-steps
  frag8 bfr[4][8];
#pragma unroll
  for (int ch = 0; ch < 4; ch++)
#pragma unroll
    for (int kc = 0; kc < 8; kc++)
      bfr[ch][kc].s = *(const short8*)(Wct + (size_t)(ch * 256 + cgp * 16 + l15) * 256 + kc * 32 + q * 8);

  int col = cgp * 16 + l15;
  int rowq = rb * 16 + q * 4;
  const ushort_t* aptr = hbuf + (size_t)(rb * 16 + l15) * 256 + q * 8;
  const float* cbase = C0 + (size_t)col * 256 + rowq;

  f32x4 cur[5], nxt[5];
#pragma unroll
  for (int c = 0; c < 5; c++) cur[c] = *(const f32x4*)(cbase + (size_t)c * 65536);

  for (int t = 0; t < T_; t++) {
    // prefetch next step's constants (independent of h; hides HBM latency under MFMA+sync)
    if (t + 1 < T_) {
#pragma unroll
      for (int c = 0; c < 5; c++)
        nxt[c] = *(const f32x4*)(cbase + ((size_t)(t + 1) * 5 + c) * 65536);
    }
    const ushort_t* hin = aptr + (size_t)(t & 1) * 65536;
    f32x4 acc[4] = {};
#pragma unroll
    for (int kc = 0; kc < 8; kc++) {
      frag8 a; a.s = *(const short8*)(hin + kc * 32);
#pragma unroll
      for (int ch = 0; ch < 4; ch++)
        acc[ch] = __builtin_amdgcn_mfma_f32_16x16x32_bf16(a.b, bfr[ch][kc].b, acc[ch], 0, 0, 0);
    }
    ushort_t* hout = hbuf + (size_t)((t + 1) & 1) * 65536;
#pragma unroll
    for (int i = 0; i < 4; i++) {
      float henc = acc[0][i] + cur[0][i];
      float rp   = acc[1][i] + cur[1][i];
      float zp   = acc[2][i] + cur[2][i];
      float hn   = acc[3][i] + cur[3][i];
      float inn  = cur[4][i];
      float rg = 1.f / (1.f + expf(-rp));
      float zg = 1.f / (1.f + expf(-zp));
      float ng = tanhf(inn + rg * hn);
      float hv = (1.f - zg) * ng + zg * henc;
      hout[(size_t)(rowq + i) * 256 + col] = f2bf(hv);
      if (t == T_ - 1) outF[(size_t)(rowq + i) * 256 + col] = hv;
    }
    if (t < T_ - 1) grid.sync();
#pragma unroll
    for (int c = 0; c < 5; c++) cur[c] = nxt[c];
  }
}

// ---------------- launch ----------------
extern "C" void kernel_launch(void* const* d_in, const int* in_sizes, int n_in,
                              void* d_out, int out_size, void* d_ws, size_t ws_size,
                              hipStream_t stream) {
  const float* obs     = (const float*)d_in[0];
  const float* actions = (const float*)d_in[1];
  const float* W1  = (const float*)d_in[2];
  const float* b1  = (const float*)d_in[3];
  const float* g1  = (const float*)d_in[4];
  const float* be1 = (const float*)d_in[5];
  const float* W2  = (const float*)d_in[6];
  const float* b2  = (const float*)d_in[7];
  const float* g2  = (const float*)d_in[8];
  const float* be2 = (const float*)d_in[9];
  const float* W3  = (const float*)d_in[10];
  const float* b3  = (const float*)d_in[11];
  const float* Wih = (const float*)d_in[12];
  const float* bih = (const float*)d_in[13];
  const float* Whh = (const float*)d_in[14];
  const float* bhh = (const float*)d_in[15];
  const float* Whe = (const float*)d_in[16];
  const float* bhe = (const float*)d_in[17];
  const float* Wae = (const float*)d_in[18];
  const float* bae = (const float*)d_in[19];

  char* ws = (char*)d_ws;
  float*    C0    = (float*)(ws + OFF_C0);
  ushort_t* obsb  = (ushort_t*)(ws + OFF_OBSB);
  float*    Y     = (float*)(ws + OFF_Y);
  float*    Yg    = (float*)(ws + OFF_YG);
  ushort_t* Xb    = (ushort_t*)(ws + OFF_XB);
  ushort_t* XG    = (ushort_t*)(ws + OFF_XG);
  ushort_t* Pencb = (ushort_t*)(ws + OFF_PENCB);
  float*    AE    = (float*)(ws + OFF_AE);
  ushort_t* W1t   = (ushort_t*)(ws + OFF_W1T);
  ushort_t* W2t   = (ushort_t*)(ws + OFF_W2T);
  ushort_t* W3t   = (ushort_t*)(ws + OFF_W3T);
  ushort_t* Wiht  = (ushort_t*)(ws + OFF_WIHT);
  ushort_t* Whht  = (ushort_t*)(ws + OFF_WHHT);
  ushort_t* Wct   = (ushort_t*)(ws + OFF_WCT);
  float*    bsum  = (float*)(ws + OFF_BSUM);
  ushort_t* hbuf  = (ushort_t*)(ws + OFF_H0);
  float*    outF  = (float*)d_out;

  // prologue
  cast_obs_k<<<MT_, 256, 0, stream>>>(obs, obsb);
  transpose_cast_k<<<dim3(16, 32), 256, 0, stream>>>(W1, W1t, 1024, 512);
  transpose_cast_k<<<dim3(16, 16), 256, 0, stream>>>(W2, W2t, 512, 512);
  transpose_cast_k<<<dim3(8, 16),  256, 0, stream>>>(W3, W3t, 512, 256);
  transpose_cast_k<<<dim3(24, 8),  256, 0, stream>>>(Wih, Wiht, 256, 768);
  transpose_cast_k<<<dim3(24, 8),  256, 0, stream>>>(Whh, Whht, 256, 768);
  wct_a_k<<<256, 256, 0, stream>>>(Whe, Wct);
  wct_b_k<<<768, 256, 0, stream>>>(Whe, Whh, Wct);
  bsum_k<<<3, 256, 0, stream>>>(bih, bhh, bsum);
  zero_k<<<256, 256, 0, stream>>>(hbuf, 65536);          // h(t=0) = 0
  ae_k<<<MT_ * 16 / 256, 256, 0, stream>>>(actions, Wae, bae, AE);

  // MLP (parallel over all T*B rows, t-major)
  gemm_bt_k<<<dim3(512, 8), 256, 0, stream>>>(obsb, 1024, W1t, 1024, Y, 512, b1, 1024, 0, 0, 0);
  bn_elu_k<<<T_, 512, 0, stream>>>(Y, g1, be1, Xb);
  gemm_bt_k<<<dim3(512, 8), 256, 0, stream>>>(Xb, 512, W2t, 512, Y, 512, b2, 512, 0, 0, 0);
  bn_elu_k<<<T_, 512, 0, stream>>>(Y, g2, be2, Xb);
  gemm_bt_k<<<dim3(512, 4), 256, 0, stream>>>(Xb, 512, W3t, 512, Yg, 256, b3, 512, 0, 0, 0);
  cast_k<<<MT_ * 256 / 256, 256, 0, stream>>>(Yg, XG, (long)MT_ * 256);

  // per-step constants into C0 (col-major per t): chunk0 henc; 1,2 rpre/zpre; 3 hn0; 4 inn
  penc_rm_k<<<MT_, 256, 0, stream>>>(AE, Whe, bhe, Pencb);
  penc_cm_k<<<T_, 256, 0, stream>>>(AE, Whe, bhe, C0);
  gemm_bt_k<<<dim3(512, 8), 256, 0, stream>>>(XG, 256, Wiht, 256, C0, 256, bsum, 256, 0, 1, 1);
  gemm_bt_k<<<dim3(512, 8), 256, 0, stream>>>(Pencb, 256, Whht, 256, C0, 256, nullptr, 256, 1, 1, 1);
  gemm_bt_k<<<dim3(512, 4), 256, 0, stream>>>(Pencb, 256, Whht + 512 * 256, 256, C0, 256, bhh + 512, 256, 0, 1, 3);
  gemm_bt_k<<<dim3(512, 4), 256, 0, stream>>>(XG, 256, Wiht + 512 * 256, 256, C0, 256, bih + 512, 256, 0, 1, 4);

  // sequential recurrence: one cooperative kernel, grid.sync() per step
  {
    void* args[] = { (void*)&Wct, (void*)&C0, (void*)&hbuf, (void*)&outF };
    hipLaunchCooperativeKernel((void*)gru_seq_k, dim3(256), dim3(64), args, 0, stream);
  }
}